// Round 2
// baseline (695.160 us; speedup 1.0000x reference)
//
#include <hip/hip_runtime.h>
#include <math.h>

#define N_NODES 40000
#define N_EDGES 640000
#define HID 128
#define MAXW 64      // in-degree ~ Poisson(16); P(deg > 64) ~ 1e-19 -> never drops edges
#define ITERS 8      // full iterations after initial state = tanh(xproj)
#define NH (N_NODES * HID)
#define NPB 16                  // nodes per fused block
#define FBLK (N_NODES / NPB)    // 2500 fused blocks
#define DSTRIDE 32              // degree-counter pad: 1 counter per 128B line
#define NN1 (N_NODES + 1)       // +1 pad row per slice
#define SLICES 4
#define SW 32                   // features per slice (32 bf16 = 64 B rows)

typedef __bf16 bf16x8 __attribute__((ext_vector_type(8)));
typedef __bf16 bf16x4 __attribute__((ext_vector_type(4)));
typedef float floatx4 __attribute__((ext_vector_type(4)));
typedef int intx4 __attribute__((ext_vector_type(4)));

union V16 { bf16x8 b; floatx4 f; };

// Fill ELL with pad index N_NODES, zero padded deg counters, zero per-slice pad rows.
__global__ __launch_bounds__(256) void init_kernel(int* __restrict__ ell,
                                                   int* __restrict__ degp,
                                                   __bf16* __restrict__ padA,
                                                   __bf16* __restrict__ padB) {
    int i = blockIdx.x * 256 + threadIdx.x;   // N_EDGES threads
    int4 pad = {N_NODES, N_NODES, N_NODES, N_NODES};
    ((int4*)ell)[i] = pad;                    // N*MAXW/4 = 640000 int4 exactly
    if (i < N_NODES * DSTRIDE / 4) {
        int4 z = {0, 0, 0, 0};
        ((int4*)degp)[i] = z;                 // 320000 int4
    }
    if (i < 16) {                             // 4 slices x 4 chunks x bf16x8 per buffer
        bf16x8 z;
#pragma unroll
        for (int j = 0; j < 8; ++j) z[j] = (__bf16)0.f;
        size_t off = ((size_t)(i >> 2) * NN1 + N_NODES) * SW + (i & 3) * 8;
        *(bf16x8*)(padA + off) = z;
        *(bf16x8*)(padB + off) = z;
    }
}

// Degree counters padded to one per 128B L2 line (round 6/7/8 lesson).
__global__ __launch_bounds__(256) void build_ell_kernel(const int* __restrict__ ei,
                                                        int* __restrict__ degp,
                                                        int* __restrict__ ell) {
    int e = blockIdx.x * 256 + threadIdx.x;
    if (e >= N_EDGES) return;
    int s = ei[e];            // src
    int d = ei[N_EDGES + e];  // dst
    int c = atomicAdd(&degp[d * DSTRIDE], 1);
    if (c < MAXW) ell[d * MAXW + c] = s;
}

__global__ __launch_bounds__(256) void compact_deg_kernel(const int* __restrict__ degp,
                                                          int* __restrict__ deg) {
    int i = blockIdx.x * 256 + threadIdx.x;
    if (i >= N_NODES) return;
    int d = degp[i * DSTRIDE];
    deg[i] = d > MAXW ? MAXW : d;
}

// Pack W (or W^T) into B-fragment order for mfma_f32_16x16x32_bf16:
// pk[((c*8+t)*64 + lane)*8 + j] = B[k = c*32 + (lane>>4)*8 + j][n = t*16 + (lane&15)]
__global__ __launch_bounds__(256) void pack_w_kernel(const float* __restrict__ w,
                                                     __bf16* __restrict__ pk, int trans) {
    int f = blockIdx.x * 256 + threadIdx.x;  // 16384 total
    int j = f & 7, l = (f >> 3) & 63, t = (f >> 9) & 7, c = f >> 12;
    int k = c * 32 + (l >> 4) * 8 + j;
    int n = t * 16 + (l & 15);
    float v = trans ? w[n * HID + k] : w[k * HID + n];
    pk[f] = (__bf16)v;
}

// Cast x -> bf16 in SLICED layout: o[slice][node][32].
__global__ __launch_bounds__(256) void cast_bf16_kernel(const float* __restrict__ x,
                                                        __bf16* __restrict__ o) {
    int i = blockIdx.x * 256 + threadIdx.x;   // NH/4 threads, one float4 each
    float4 v = ((const float4*)x)[i];
    bf16x4 b;
    b[0] = (__bf16)v.x; b[1] = (__bf16)v.y; b[2] = (__bf16)v.z; b[3] = (__bf16)v.w;
    int node = i >> 5;          // 32 float4 per 128-f row
    int r = i & 31;
    int slice = r >> 3;         // 8 float4 per 32-f slice
    int within = (r & 7) * 4;
    *(bf16x4*)(o + ((size_t)slice * NN1 + node) * SW + within) = b;
}

// xproj GEMM (runs twice): xp_bf = A @ B (bf16 pre-tanh, ROW-major),
// st_bf = tanh(...) written SLICED (it seeds the fused gather).
// A is read in SLICED layout (x_bf for layer 0, h0 state for layer 1).
__global__ __launch_bounds__(256) void mfma_gemm_kernel(const __bf16* A,
                                                        const __bf16* __restrict__ Bpk,
                                                        __bf16* __restrict__ xp_bf,
                                                        __bf16* st_bf) {
    __shared__ float tile[4][16][132];
    int tid = threadIdx.x;
    int wv = tid >> 6, lane = tid & 63;
    int q = lane >> 4, cl = lane & 15;

    int row_a = blockIdx.x * 64 + wv * 16 + cl;
    bf16x8 a[4];
#pragma unroll
    for (int c = 0; c < 4; ++c)   // features c*32 + q*8.. live in slice c
        a[c] = *(const bf16x8*)(A + ((size_t)c * NN1 + row_a) * SW + q * 8);

#pragma unroll
    for (int t = 0; t < 8; ++t) {
        floatx4 acc_t = {0.f, 0.f, 0.f, 0.f};
#pragma unroll
        for (int c = 0; c < 4; ++c) {
            bf16x8 b = *(const bf16x8*)(Bpk + (((c * 8 + t) * 64 + lane) << 3));
            acc_t = __builtin_amdgcn_mfma_f32_16x16x32_bf16(a[c], b, acc_t, 0, 0, 0);
        }
#pragma unroll
        for (int r = 0; r < 4; ++r)
            tile[wv][q * 4 + r][t * 16 + cl] = acc_t[r];
    }
    __syncthreads();
    int row = lane >> 2, seg = lane & 3;
    int grow = blockIdx.x * 64 + wv * 16 + row;
    size_t goff = (size_t)grow * HID + seg * 32;
    float v[32];
#pragma unroll
    for (int j = 0; j < 8; ++j) {
        floatx4 t4 = *(floatx4*)&tile[wv][row][seg * 32 + j * 4];
        v[j * 4] = t4[0]; v[j * 4 + 1] = t4[1]; v[j * 4 + 2] = t4[2]; v[j * 4 + 3] = t4[3];
    }
#pragma unroll
    for (int j = 0; j < 4; ++j) {
        bf16x8 o;
#pragma unroll
        for (int k = 0; k < 8; ++k) o[k] = (__bf16)v[j * 8 + k];
        *(bf16x8*)(xp_bf + goff + j * 8) = o;   // pre-tanh, bf16, row-major
    }
#pragma unroll
    for (int i = 0; i < 32; ++i) v[i] = tanhf(v[i]);
    // features seg*32 + j*8 .. live in slice seg
#pragma unroll
    for (int j = 0; j < 4; ++j) {
        bf16x8 o;
#pragma unroll
        for (int k = 0; k < 8; ++k) o[k] = (__bf16)v[j * 8 + k];
        *(bf16x8*)(st_bf + ((size_t)seg * NN1 + grow) * SW + j * 8) = o;
    }
}

// Fused iteration: state_out = tanh(xproj + gather(state_in) @ W).
// SLICE-MAJOR gather: state is [slice][node][32] bf16; each 2.56 MB slice fits a
// per-XCD 4 MiB L2, and all co-resident blocks walk slices in the same order ->
// the random gather is served from L2 (~34.5 TB/s agg) instead of the L3/fabric
// ceiling (~6.5 TB/s) that bounded the full-row pull at 28.5 us/iter.
// Streaming traffic (ELL stage, xproj, state/out writes) is nontemporal so it
// doesn't evict the gather slice.
// Per quarter: node n = wv*4+q; lane sub=f>>2 owns neighbor slot b0+sub, chunk
// fc=f&3 owns features fc*8..+8 of the slice; 2-step shfl_xor tree sums subs.
__global__ __launch_bounds__(256, 8) void fused_iter_kernel(
    const __bf16* __restrict__ state_in,
    __bf16* __restrict__ state_out,
    const int* __restrict__ ell,
    const int* __restrict__ deg,
    const __bf16* __restrict__ Bpk,
    const __bf16* __restrict__ xproj,
    float* __restrict__ st_f32) {
    __shared__ __align__(16) char smem[8704];
    int(*ell_lds)[68] = (int(*)[68])smem;                    // [16][68] int: 4352 B
    __bf16(*aggr_lds)[136] = (__bf16(*)[136])(smem + 4352);  // [16][136]: 4352 B
    float(*tile)[132] = (float(*)[132])smem;                 // [16][132] f32: 8448 B

    int tid = threadIdx.x;
    int wv = tid >> 6, lane = tid & 63;
    int q = lane >> 4, f = lane & 15;
    int nb = blockIdx.x * NPB;

    int degv = deg[nb + f];   // already clamped to MAXW
    // block max degree via 16-lane butterfly (no atomics)
    int bmx = degv;
#pragma unroll
    for (int m = 1; m <= 8; m <<= 1) {
        int o = __shfl_xor(bmx, m);
        bmx = o > bmx ? o : bmx;
    }
    int nslots = (bmx + 3) & ~3;

    // stage ELL: 256 threads = 16 rows x 16 int4-groups, one shot, masked, nt
    {
        int n = tid & 15, g = tid >> 4;
        if (g * 4 < nslots) {
            intx4 e4 = __builtin_nontemporal_load(
                (const intx4*)&ell[(size_t)(nb + n) * MAXW + g * 4]);
            *(intx4*)&ell_lds[n][g * 4] = e4;
        }
    }
    __syncthreads();

    // ---- phase 1: quarter q of wave wv gathers node n = wv*4+q, slice-major ----
    int n = wv * 4 + q;
    int cn = __shfl(degv, n);          // lane n holds deg[nb+n]
    int steps = (cn + 3) >> 2;         // exact 4-granular trip count
    int sub = f >> 2;                  // neighbor sub-lane 0..3
    int fc = f & 3;                    // feature chunk 0..3 (8 bf16 each)
    for (int s = 0; s < SLICES; ++s) {
        const __bf16* sl = state_in + (size_t)s * NN1 * SW;
        float acc[8];
#pragma unroll
        for (int j = 0; j < 8; ++j) acc[j] = 0.f;
        for (int st = 0; st < steps; ++st) {
            int idxm = ell_lds[n][st * 4 + sub];
            bf16x8 v = *(const bf16x8*)(sl + (size_t)idxm * SW + fc * 8);
#pragma unroll
            for (int j = 0; j < 8; ++j) acc[j] += (float)v[j];
        }
        // sum the 4 neighbor sub-lanes (stays inside the 16-lane quarter)
#pragma unroll
        for (int j = 0; j < 8; ++j) {
            acc[j] += __shfl_xor(acc[j], 4);
            acc[j] += __shfl_xor(acc[j], 8);
        }
        if (sub == 0) {
            bf16x8 o;
#pragma unroll
            for (int j = 0; j < 8; ++j) o[j] = (__bf16)acc[j];
            *(bf16x8*)&aggr_lds[n][s * SW + fc * 8] = o;
        }
    }
    __syncthreads();

    // ---- phase 2: M=16 GEMM; wave wv owns output cols wv*32 .. +31 ----
    bf16x8 a[4];
#pragma unroll
    for (int c = 0; c < 4; ++c)
        a[c] = *(const bf16x8*)&aggr_lds[f][c * 32 + q * 8];
    __syncthreads();   // overlay safety: aggr/ell reads done before tile writes

#pragma unroll
    for (int tl = 0; tl < 2; ++tl) {
        int t = wv * 2 + tl;
        floatx4 acc_t = {0.f, 0.f, 0.f, 0.f};
#pragma unroll
        for (int c = 0; c < 4; ++c) {
            bf16x8 b = *(const bf16x8*)(Bpk + (((c * 8 + t) * 64 + lane) << 3));
            acc_t = __builtin_amdgcn_mfma_f32_16x16x32_bf16(a[c], b, acc_t, 0, 0, 0);
        }
#pragma unroll
        for (int r = 0; r < 4; ++r)
            tile[q * 4 + r][t * 16 + f] = acc_t[r];
    }
    __syncthreads();

    // epilogue (wave-private cols): rows 0..15, cols wv*32 + (lane&3)*8 .. +7
    int row = lane >> 2, seg = lane & 3;
    int grow = nb + row;
    size_t goff = (size_t)grow * HID + wv * 32 + seg * 8;   // row-major (xproj, f32 out)
    int lcol = wv * 32 + seg * 8;
    float v[8];
    floatx4 bxt = __builtin_nontemporal_load((const floatx4*)(xproj + goff));
    V16 ubx; ubx.f = bxt;
    bf16x8 bx = ubx.b;
#pragma unroll
    for (int j = 0; j < 2; ++j) {
        floatx4 t4 = *(floatx4*)&tile[row][lcol + j * 4];
        v[j * 4] = t4[0]; v[j * 4 + 1] = t4[1]; v[j * 4 + 2] = t4[2]; v[j * 4 + 3] = t4[3];
    }
#pragma unroll
    for (int k = 0; k < 8; ++k) v[k] = tanhf(v[k] + (float)bx[k]);
    {
        bf16x8 o;
#pragma unroll
        for (int k = 0; k < 8; ++k) o[k] = (__bf16)v[k];
        // features wv*32 + seg*8.. live in slice wv
        V16 uo; uo.b = o;
        __builtin_nontemporal_store(
            uo.f, (floatx4*)(state_out + ((size_t)wv * NN1 + grow) * SW + seg * 8));
    }
    if (st_f32) {
#pragma unroll
        for (int j = 0; j < 2; ++j) {
            floatx4 o = {v[j * 4], v[j * 4 + 1], v[j * 4 + 2], v[j * 4 + 3]};
            __builtin_nontemporal_store(o, (floatx4*)(st_f32 + goff + j * 4));
        }
    }
}

extern "C" void kernel_launch(void* const* d_in, const int* in_sizes, int n_in,
                              void* d_out, int out_size, void* d_ws, size_t ws_size,
                              hipStream_t stream) {
    const int* ei = (const int*)d_in[0];       // edge_index [2][E]
    const float* x = (const float*)d_in[1];    // [N][128] f32
    const float* w_in0 = (const float*)d_in[2];
    const float* w_rec0 = (const float*)d_in[3];
    const float* w_in1 = (const float*)d_in[4];
    const float* w_rec1 = (const float*)d_in[5];
    float* out = (float*)d_out;

    // workspace carve (~47 MB total); sliced state = 4*NN1*32 = NH+128 elems
    __bf16* xproj_bf = (__bf16*)d_ws;              // NH bf16 (10.24 MB), row-major
    __bf16* stateA = xproj_bf + NH;                // sliced [4][NN1][32]
    __bf16* stateB = stateA + (size_t)SLICES * NN1 * SW;  // sliced; x_bf first
    __bf16* packs = stateB + (size_t)SLICES * NN1 * SW;   // 4 x 16384 bf16
    int* deg = (int*)(packs + 4 * 16384);          // N (compact)
    int* degp = deg + N_NODES;                     // N*DSTRIDE (5.12 MB, padded counters)
    int* ell = degp + N_NODES * DSTRIDE;           // N*MAXW (10.24 MB)
    __bf16* pk_in0 = packs;
    __bf16* pk_rec0 = packs + 16384;
    __bf16* pk_in1 = packs + 2 * 16384;
    __bf16* pk_rec1 = packs + 3 * 16384;

    init_kernel<<<N_EDGES / 256, 256, 0, stream>>>(ell, degp, stateA, stateB);
    build_ell_kernel<<<N_EDGES / 256, 256, 0, stream>>>(ei, degp, ell);
    compact_deg_kernel<<<(N_NODES + 255) / 256, 256, 0, stream>>>(degp, deg);
    pack_w_kernel<<<64, 256, 0, stream>>>(w_in0, pk_in0, 1);   // B = w_in0^T
    pack_w_kernel<<<64, 256, 0, stream>>>(w_rec0, pk_rec0, 0); // B = w_rec0
    pack_w_kernel<<<64, 256, 0, stream>>>(w_in1, pk_in1, 1);
    pack_w_kernel<<<64, 256, 0, stream>>>(w_rec1, pk_rec1, 0);
    cast_bf16_kernel<<<NH / 4 / 256, 256, 0, stream>>>(x, stateB);  // x_bf sliced

    for (int layer = 0; layer < 2; ++layer) {
        const __bf16* pk_in = layer ? pk_in1 : pk_in0;
        const __bf16* pk_rec = layer ? pk_rec1 : pk_rec0;
        // xproj = (layer ? h0 : x_bf) @ w_in^T ; stateA = tanh(xproj), sliced.
        // layer 1: A aliases st_bf (each wave loads its own rows into regs before
        // any store — rows are wave-private, safe).
        const __bf16* xin = layer ? stateA : stateB;
        mfma_gemm_kernel<<<625, 256, 0, stream>>>(xin, pk_in, xproj_bf, stateA);
        // 8 ping-pong iterations: A->B, B->A, ... ends in stateA.
        for (int it = 0; it < ITERS; ++it) {
            const __bf16* sin = (it & 1) ? stateB : stateA;
            __bf16* sout = (it & 1) ? stateA : stateB;
            float* f32out = (layer == 1 && it == ITERS - 1) ? out : nullptr;
            fused_iter_kernel<<<FBLK, 256, 0, stream>>>(sin, sout, ell, deg,
                                                        pk_rec, xproj_bf, f32out);
        }
    }
}

// Round 8
// 685.629 us; speedup vs baseline: 1.0139x; 1.0139x over previous
//
#include <hip/hip_runtime.h>
#include <math.h>

#define N_NODES 40000
#define N_EDGES 640000
#define HID 128
#define HHID 64                          // features per plane
#define PLANE ((N_NODES + 1) * HHID)     // elems per plane incl zero pad row
#define MAXW 64      // in-degree ~ Poisson(16); P(deg > 64) ~ 1e-19 -> never drops edges
#define ITERS 8
#define NH (N_NODES * HID)
#define NPB 16                  // nodes per fused block
#define FBLK (N_NODES / NPB)    // 2500 fused blocks
#define DSTRIDE 32              // degree-counter pad: 1 counter per 128B line

typedef __bf16 bf16x8 __attribute__((ext_vector_type(8)));
typedef __bf16 bf16x4 __attribute__((ext_vector_type(4)));
typedef float floatx4 __attribute__((ext_vector_type(4)));
typedef int intx4 __attribute__((ext_vector_type(4)));

union V16 { bf16x8 b; floatx4 f; };

// Fill ELL with pad index N_NODES, zero deg counters, zero the 4 plane pad rows.
__global__ __launch_bounds__(256) void init_kernel(int* __restrict__ ell,
                                                   int* __restrict__ degp,
                                                   __bf16* __restrict__ stA,
                                                   __bf16* __restrict__ stB) {
    int i = blockIdx.x * 256 + threadIdx.x;   // N_EDGES threads
    int4 pad = {N_NODES, N_NODES, N_NODES, N_NODES};
    ((int4*)ell)[i] = pad;                    // N*MAXW/4 = 640000 int4 exactly
    if (i < N_NODES * DSTRIDE / 4) {
        int4 z = {0, 0, 0, 0};
        ((int4*)degp)[i] = z;                 // 320000 int4
    }
    if (i < 8) {                              // 8 x 16B = 128B pad row per plane
        bf16x8 z;
#pragma unroll
        for (int j = 0; j < 8; ++j) z[j] = (__bf16)0.f;
        *(bf16x8*)(stA + (size_t)N_NODES * HHID + i * 8) = z;           // A plane0
        *(bf16x8*)(stA + PLANE + (size_t)N_NODES * HHID + i * 8) = z;   // A plane1
        *(bf16x8*)(stB + (size_t)N_NODES * HHID + i * 8) = z;           // B plane0
        *(bf16x8*)(stB + PLANE + (size_t)N_NODES * HHID + i * 8) = z;   // B plane1
    }
}

// Degree counters padded to one per 128B L2 line.
__global__ __launch_bounds__(256) void build_ell_kernel(const int* __restrict__ ei,
                                                        int* __restrict__ degp,
                                                        int* __restrict__ ell) {
    int e = blockIdx.x * 256 + threadIdx.x;
    if (e >= N_EDGES) return;
    int s = ei[e];            // src
    int d = ei[N_EDGES + e];  // dst
    int c = atomicAdd(&degp[d * DSTRIDE], 1);
    if (c < MAXW) ell[d * MAXW + c] = s;
}

__global__ __launch_bounds__(256) void compact_deg_kernel(const int* __restrict__ degp,
                                                          int* __restrict__ deg) {
    int i = blockIdx.x * 256 + threadIdx.x;
    if (i >= N_NODES) return;
    int d = degp[i * DSTRIDE];
    deg[i] = d > MAXW ? MAXW : d;
}

// Pack W (or W^T) into B-fragment order for mfma_f32_16x16x32_bf16:
// pk[((c*8+t)*64 + lane)*8 + j] = B[k = c*32 + (lane>>4)*8 + j][n = t*16 + (lane&15)]
__global__ __launch_bounds__(256) void pack_w_kernel(const float* __restrict__ w,
                                                     __bf16* __restrict__ pk, int trans) {
    int f = blockIdx.x * 256 + threadIdx.x;  // 16384 total
    int j = f & 7, l = (f >> 3) & 63, t = (f >> 9) & 7, c = f >> 12;
    int k = c * 32 + (l >> 4) * 8 + j;
    int n = t * 16 + (l & 15);
    float v = trans ? w[n * HID + k] : w[k * HID + n];
    pk[f] = (__bf16)v;
}

// Cast x f32 row-major -> planar bf16 [2][N][64].
__global__ __launch_bounds__(256) void cast_planar_kernel(const float* __restrict__ x,
                                                          __bf16* __restrict__ st) {
    int i = blockIdx.x * 256 + threadIdx.x;   // NH/4 threads, one float4 each
    float4 v = ((const float4*)x)[i];
    bf16x4 b;
    b[0] = (__bf16)v.x; b[1] = (__bf16)v.y; b[2] = (__bf16)v.z; b[3] = (__bf16)v.w;
    int node = i >> 5;          // 32 float4 per 128-f row
    int r = i & 31;             // feature chunk r*4
    int plane = r >> 4;
    *(bf16x4*)(st + (size_t)plane * PLANE + (size_t)node * HHID + (r & 15) * 4) = b;
}

// xproj GEMM (runs twice): A read PLANAR, xp_bf = A@B bf16 row-major (pre-tanh),
// st = tanh(...) written PLANAR (seeds the fused gather).
__global__ __launch_bounds__(256) void mfma_gemm_kernel(const __bf16* A,
                                                        const __bf16* __restrict__ Bpk,
                                                        __bf16* __restrict__ xp_bf,
                                                        __bf16* __restrict__ st) {
    __shared__ float tile[4][16][132];
    int tid = threadIdx.x;
    int wv = tid >> 6, lane = tid & 63;
    int q = lane >> 4, cl = lane & 15;

    int row_a = blockIdx.x * 64 + wv * 16 + cl;
    bf16x8 a[4];
#pragma unroll
    for (int c = 0; c < 4; ++c)   // features c*32+q*8: plane c>>1, within (c&1)*32+q*8
        a[c] = *(const bf16x8*)(A + (size_t)(c >> 1) * PLANE + (size_t)row_a * HHID +
                                (c & 1) * 32 + q * 8);

#pragma unroll
    for (int t = 0; t < 8; ++t) {
        floatx4 acc_t = {0.f, 0.f, 0.f, 0.f};
#pragma unroll
        for (int c = 0; c < 4; ++c) {
            bf16x8 b = *(const bf16x8*)(Bpk + (((c * 8 + t) * 64 + lane) << 3));
            acc_t = __builtin_amdgcn_mfma_f32_16x16x32_bf16(a[c], b, acc_t, 0, 0, 0);
        }
#pragma unroll
        for (int r = 0; r < 4; ++r)
            tile[wv][q * 4 + r][t * 16 + cl] = acc_t[r];
    }
    int row = lane >> 2, seg = lane & 3;
    int grow = blockIdx.x * 64 + wv * 16 + row;
    size_t goff = (size_t)grow * HID + seg * 32;
    float v[32];
#pragma unroll
    for (int j = 0; j < 8; ++j) {
        floatx4 t4 = *(floatx4*)&tile[wv][row][seg * 32 + j * 4];
        v[j * 4] = t4[0]; v[j * 4 + 1] = t4[1]; v[j * 4 + 2] = t4[2]; v[j * 4 + 3] = t4[3];
    }
#pragma unroll
    for (int j = 0; j < 4; ++j) {
        bf16x8 o;
#pragma unroll
        for (int k = 0; k < 8; ++k) o[k] = (__bf16)v[j * 8 + k];
        *(bf16x8*)(xp_bf + goff + j * 8) = o;   // pre-tanh, bf16, row-major
    }
#pragma unroll
    for (int i = 0; i < 32; ++i) v[i] = tanhf(v[i]);
    // planar state: features seg*32.. -> plane seg>>1, within (seg&1)*32
    {
        __bf16* sb = st + (size_t)(seg >> 1) * PLANE + (size_t)grow * HHID + (seg & 1) * 32;
#pragma unroll
        for (int j = 0; j < 4; ++j) {
            bf16x8 o;
#pragma unroll
            for (int k = 0; k < 8; ++k) o[k] = (__bf16)v[j * 8 + k];
            *(bf16x8*)(sb + j * 8) = o;
        }
    }
}

// k1: gather PLANE 0 (features 0..63) for the block's 16 nodes -> aggr0 scratch.
// The kernel boundary after k1 is a global barrier: all blocks GPU-wide touch
// only this 5.12 MB plane (dense 128B rows = 1 line each) -> per-XCD L2 holds
// most of it, gather served from L2 instead of the ~6.5 TB/s L3/fabric path.
__global__ __launch_bounds__(256, 8) void gather1_kernel(
    const __bf16* __restrict__ state_in,   // plane0 base
    __bf16* __restrict__ aggr0,
    const int* __restrict__ ell,
    const int* __restrict__ deg) {
    __shared__ __align__(16) int ell_lds[16][68];

    int tid = threadIdx.x;
    int wv = tid >> 6, lane = tid & 63;
    int q = lane >> 4, f = lane & 15;
    int nb = blockIdx.x * NPB;

    int degv = deg[nb + f];
    int bmx = degv;
#pragma unroll
    for (int m = 1; m <= 8; m <<= 1) {
        int o = __shfl_xor(bmx, m);
        bmx = o > bmx ? o : bmx;
    }
    int nslots = (bmx + 3) & ~3;
    {
        int n = tid & 15, g = tid >> 4;
        if (g * 4 < nslots) {
            intx4 e4 = __builtin_nontemporal_load(
                (const intx4*)&ell[(size_t)(nb + n) * MAXW + g * 4]);
            *(intx4*)&ell_lds[n][g * 4] = e4;
        }
    }
    __syncthreads();

    // quarter q of wave wv gathers node n; lane f covers features f*4..f*4+3 (8B)
    int n = wv * 4 + q;
    int cn = __shfl(degv, n);
    int steps = (cn + 3) >> 2;
    float acc[4];
#pragma unroll
    for (int j = 0; j < 4; ++j) acc[j] = 0.f;
    for (int s = 0; s < steps; ++s) {
        int b0 = s * 4;
        int idx[4];
#pragma unroll
        for (int u = 0; u < 4; ++u) idx[u] = ell_lds[n][b0 + u];
        bf16x4 v[4];
#pragma unroll
        for (int u = 0; u < 4; ++u)
            v[u] = *(const bf16x4*)(state_in + (size_t)idx[u] * HHID + f * 4);
#pragma unroll
        for (int j = 0; j < 4; ++j)
            acc[j] += ((float)v[0][j] + (float)v[1][j]) + ((float)v[2][j] + (float)v[3][j]);
    }
    {
        bf16x4 o;
#pragma unroll
        for (int j = 0; j < 4; ++j) o[j] = (__bf16)acc[j];
        *(bf16x4*)(aggr0 + (size_t)(nb + n) * HHID + f * 4) = o;
    }
}

// k2: gather PLANE 1, load aggr0, full M=16 GEMM, tanh, planar state write.
__global__ __launch_bounds__(256, 8) void fused2_kernel(
    const __bf16* __restrict__ state_in,   // buffer base (plane1 = +PLANE)
    __bf16* __restrict__ state_out,
    const int* __restrict__ ell,
    const int* __restrict__ deg,
    const __bf16* __restrict__ Bpk,
    const __bf16* __restrict__ xproj,
    const __bf16* __restrict__ aggr0,
    float* __restrict__ st_f32) {
    __shared__ __align__(16) char smem[8704];
    int(*ell_lds)[68] = (int(*)[68])smem;                    // [16][68] int: 4352 B
    __bf16(*aggr_lds)[136] = (__bf16(*)[136])(smem + 4352);  // [16][136]: 4352 B
    float(*tile)[132] = (float(*)[132])smem;                 // [16][132] f32 overlay

    int tid = threadIdx.x;
    int wv = tid >> 6, lane = tid & 63;
    int q = lane >> 4, f = lane & 15;
    int nb = blockIdx.x * NPB;

    int degv = deg[nb + f];
    int bmx = degv;
#pragma unroll
    for (int m = 1; m <= 8; m <<= 1) {
        int o = __shfl_xor(bmx, m);
        bmx = o > bmx ? o : bmx;
    }
    int nslots = (bmx + 3) & ~3;
    {
        int n = tid & 15, g = tid >> 4;
        if (g * 4 < nslots) {
            intx4 e4 = __builtin_nontemporal_load(
                (const intx4*)&ell[(size_t)(nb + n) * MAXW + g * 4]);
            *(intx4*)&ell_lds[n][g * 4] = e4;
        }
    }
    __syncthreads();

    // stage aggr0 rows for the block's nodes: 16 nodes x 16 lanes x 8B
    {
        int n = tid >> 4, l = tid & 15;
        *(bf16x4*)&aggr_lds[n][l * 4] =
            *(const bf16x4*)(aggr0 + (size_t)(nb + n) * HHID + l * 4);
    }

    // gather plane1: lane f covers global features 64 + f*4..+3
    const __bf16* sin1 = state_in + PLANE;
    int n = wv * 4 + q;
    int cn = __shfl(degv, n);
    int steps = (cn + 3) >> 2;
    float acc[4];
#pragma unroll
    for (int j = 0; j < 4; ++j) acc[j] = 0.f;
    for (int s = 0; s < steps; ++s) {
        int b0 = s * 4;
        int idx[4];
#pragma unroll
        for (int u = 0; u < 4; ++u) idx[u] = ell_lds[n][b0 + u];
        bf16x4 v[4];
#pragma unroll
        for (int u = 0; u < 4; ++u)
            v[u] = *(const bf16x4*)(sin1 + (size_t)idx[u] * HHID + f * 4);
#pragma unroll
        for (int j = 0; j < 4; ++j)
            acc[j] += ((float)v[0][j] + (float)v[1][j]) + ((float)v[2][j] + (float)v[3][j]);
    }
    {
        bf16x4 o;
#pragma unroll
        for (int j = 0; j < 4; ++j) o[j] = (__bf16)acc[j];
        *(bf16x4*)&aggr_lds[n][64 + f * 4] = o;
    }
    __syncthreads();

    // ---- phase 2: M=16 GEMM; wave wv owns output cols wv*32 .. +31 ----
    bf16x8 a[4];
#pragma unroll
    for (int c = 0; c < 4; ++c)
        a[c] = *(const bf16x8*)&aggr_lds[f][c * 32 + q * 8];
    __syncthreads();   // overlay safety: aggr/ell reads done before tile writes

#pragma unroll
    for (int tl = 0; tl < 2; ++tl) {
        int t = wv * 2 + tl;
        floatx4 acc_t = {0.f, 0.f, 0.f, 0.f};
#pragma unroll
        for (int c = 0; c < 4; ++c) {
            bf16x8 b = *(const bf16x8*)(Bpk + (((c * 8 + t) * 64 + lane) << 3));
            acc_t = __builtin_amdgcn_mfma_f32_16x16x32_bf16(a[c], b, acc_t, 0, 0, 0);
        }
#pragma unroll
        for (int r = 0; r < 4; ++r)
            tile[q * 4 + r][t * 16 + f] = acc_t[r];
    }

    // epilogue: rows 0..15, cols wv*32 + (lane&3)*8 .. +7
    int row = lane >> 2, seg = lane & 3;
    int grow = nb + row;
    size_t goff = (size_t)grow * HID + wv * 32 + seg * 8;   // row-major (xproj, f32)
    int lcol = wv * 32 + seg * 8;
    float v[8];
    V16 ubx;
    ubx.f = __builtin_nontemporal_load((const floatx4*)(xproj + goff));
    bf16x8 bx = ubx.b;
#pragma unroll
    for (int j = 0; j < 2; ++j) {
        floatx4 t4 = *(floatx4*)&tile[row][lcol + j * 4];
        v[j * 4] = t4[0]; v[j * 4 + 1] = t4[1]; v[j * 4 + 2] = t4[2]; v[j * 4 + 3] = t4[3];
    }
#pragma unroll
    for (int k = 0; k < 8; ++k) v[k] = tanhf(v[k] + (float)bx[k]);
    {
        bf16x8 o;
#pragma unroll
        for (int k = 0; k < 8; ++k) o[k] = (__bf16)v[k];
        // features wv*32+seg*8: plane wv>>1, within (wv&1)*32 + seg*8
        *(bf16x8*)(state_out + (size_t)(wv >> 1) * PLANE + (size_t)grow * HHID +
                   (wv & 1) * 32 + seg * 8) = o;
    }
    if (st_f32) {
#pragma unroll
        for (int j = 0; j < 2; ++j) {
            float4 o = {v[j * 4], v[j * 4 + 1], v[j * 4 + 2], v[j * 4 + 3]};
            *(float4*)(st_f32 + goff + j * 4) = o;
        }
    }
}

extern "C" void kernel_launch(void* const* d_in, const int* in_sizes, int n_in,
                              void* d_out, int out_size, void* d_ws, size_t ws_size,
                              hipStream_t stream) {
    const int* ei = (const int*)d_in[0];       // edge_index [2][E]
    const float* x = (const float*)d_in[1];    // [N][128] f32
    const float* w_in0 = (const float*)d_in[2];
    const float* w_rec0 = (const float*)d_in[3];
    const float* w_in1 = (const float*)d_in[4];
    const float* w_rec1 = (const float*)d_in[5];
    float* out = (float*)d_out;

    // workspace carve (~52 MB)
    __bf16* xproj_bf = (__bf16*)d_ws;              // NH bf16, row-major
    __bf16* stateA = xproj_bf + NH;                // [2][N+1][64] planar
    __bf16* stateB = stateA + 2 * PLANE;           // [2][N+1][64] planar
    __bf16* aggr0 = stateB + 2 * PLANE;            // N*64 bf16 scratch
    __bf16* packs = aggr0 + (size_t)N_NODES * HHID;  // 4 x 16384 bf16
    int* deg = (int*)(packs + 4 * 16384);          // N (compact)
    int* degp = deg + N_NODES;                     // N*DSTRIDE padded counters
    int* ell = degp + N_NODES * DSTRIDE;           // N*MAXW
    __bf16* pk_in0 = packs;
    __bf16* pk_rec0 = packs + 16384;
    __bf16* pk_in1 = packs + 2 * 16384;
    __bf16* pk_rec1 = packs + 3 * 16384;

    init_kernel<<<N_EDGES / 256, 256, 0, stream>>>(ell, degp, stateA, stateB);
    build_ell_kernel<<<N_EDGES / 256, 256, 0, stream>>>(ei, degp, ell);
    compact_deg_kernel<<<(N_NODES + 255) / 256, 256, 0, stream>>>(degp, deg);
    pack_w_kernel<<<64, 256, 0, stream>>>(w_in0, pk_in0, 1);   // B = w_in0^T
    pack_w_kernel<<<64, 256, 0, stream>>>(w_rec0, pk_rec0, 0); // B = w_rec0
    pack_w_kernel<<<64, 256, 0, stream>>>(w_in1, pk_in1, 1);
    pack_w_kernel<<<64, 256, 0, stream>>>(w_rec1, pk_rec1, 0);
    cast_planar_kernel<<<NH / 4 / 256, 256, 0, stream>>>(x, stateA);  // x planar in A

    for (int layer = 0; layer < 2; ++layer) {
        const __bf16* pk_in = layer ? pk_in1 : pk_in0;
        const __bf16* pk_rec = layer ? pk_rec1 : pk_rec0;
        // L0: A holds x -> st into B; L1: B holds h0 -> st into A. No aliasing:
        // gemm reads its A rows into regs per-wave before storing (distinct bufs).
        const __bf16* gin = layer ? stateB : stateA;
        __bf16* gst = layer ? stateA : stateB;
        mfma_gemm_kernel<<<625, 256, 0, stream>>>(gin, pk_in, xproj_bf, gst);
        for (int it = 0; it < ITERS; ++it) {
            // L0: B->A->B...; L1: A->B->A...
            const __bf16* sin;
            __bf16* sout;
            if (layer == 0) {
                sin = (it & 1) ? stateA : stateB;
                sout = (it & 1) ? stateB : stateA;
            } else {
                sin = (it & 1) ? stateB : stateA;
                sout = (it & 1) ? stateA : stateB;
            }
            float* f32out = (layer == 1 && it == ITERS - 1) ? out : nullptr;
            gather1_kernel<<<FBLK, 256, 0, stream>>>(sin, aggr0, ell, deg);
            fused2_kernel<<<FBLK, 256, 0, stream>>>(sin, sout, ell, deg,
                                                    pk_rec, xproj_bf, aggr0, f32out);
        }
    }
}

// Round 9
// 604.114 us; speedup vs baseline: 1.1507x; 1.1349x over previous
//
#include <hip/hip_runtime.h>
#include <math.h>

#define N_NODES 40000
#define N_EDGES 640000
#define HID 128
#define ITERS 8      // full iterations after initial state = tanh(xproj)
#define NH (N_NODES * HID)
#define NPB 16                  // nodes per fused block
#define FBLK (N_NODES / NPB)    // 2500 fused blocks
#define DSTRIDE 32              // degree-counter pad: 4 bucket counters in one 128B line
#define BUCK 4                  // node-range buckets (phases)
#define BSLOT 20                // slots/bucket: P(Poisson(4)>20) ~ 3e-10, never drops
#define ELLW (BUCK * BSLOT)     // 80 ints per node
#define BRANGE (N_NODES / BUCK) // 10000 nodes = 2.56 MB bf16 rows -> fits 4 MiB L2
#define LBS 24                  // LDS bucket stride (16B-aligned)

typedef __bf16 bf16x8 __attribute__((ext_vector_type(8)));
typedef __bf16 bf16x4 __attribute__((ext_vector_type(4)));
typedef float floatx4 __attribute__((ext_vector_type(4)));

// Fill ELL with pad index N_NODES, zero bucket counters, zero state pad rows.
__global__ __launch_bounds__(256) void init_kernel(int* __restrict__ ell,
                                                   int* __restrict__ degp,
                                                   __bf16* __restrict__ padA,
                                                   __bf16* __restrict__ padB) {
    int i = blockIdx.x * 256 + threadIdx.x;   // N_NODES*ELLW/4 = 800000 threads
    int4 pad = {N_NODES, N_NODES, N_NODES, N_NODES};
    ((int4*)ell)[i] = pad;                    // 800000 int4 exactly
    if (i < N_NODES * DSTRIDE / 4) {
        int4 z = {0, 0, 0, 0};
        ((int4*)degp)[i] = z;                 // 320000 int4
    }
    if (i < HID / 8) {
        bf16x8 z;
#pragma unroll
        for (int j = 0; j < 8; ++j) z[j] = (__bf16)0.f;
        ((bf16x8*)padA)[i] = z;
        ((bf16x8*)padB)[i] = z;
    }
}

// Bucketed ELL build: entries bucketed by SOURCE node range (the gathered row).
// 4 counters per node live in one 128B line (DSTRIDE pad, rounds 6/7/8 lesson).
__global__ __launch_bounds__(256) void build_ell_kernel(const int* __restrict__ ei,
                                                        int* __restrict__ degp,
                                                        int* __restrict__ ell) {
    int e = blockIdx.x * 256 + threadIdx.x;
    if (e >= N_EDGES) return;
    int s = ei[e];            // src (gathered)
    int d = ei[N_EDGES + e];  // dst
    int p = s / BRANGE;       // phase bucket by source range
    int c = atomicAdd(&degp[d * DSTRIDE + p], 1);
    if (c < BSLOT) ell[d * ELLW + p * BSLOT + c] = s;
}

// Pack the 4 bucket counts (each <= 20) into one int per node.
__global__ __launch_bounds__(256) void compact_deg_kernel(const int* __restrict__ degp,
                                                          int* __restrict__ deg) {
    int i = blockIdx.x * 256 + threadIdx.x;
    if (i >= N_NODES) return;
    int pk = 0;
#pragma unroll
    for (int p = 0; p < BUCK; ++p) {
        int c = degp[i * DSTRIDE + p];
        if (c > BSLOT) c = BSLOT;
        pk |= c << (p * 8);
    }
    deg[i] = pk;
}

// Pack W (or W^T) into B-fragment order for mfma_f32_16x16x32_bf16:
// pk[((c*8+t)*64 + lane)*8 + j] = B[k = c*32 + (lane>>4)*8 + j][n = t*16 + (lane&15)]
__global__ __launch_bounds__(256) void pack_w_kernel(const float* __restrict__ w,
                                                     __bf16* __restrict__ pk, int trans) {
    int f = blockIdx.x * 256 + threadIdx.x;  // 16384 total
    int j = f & 7, l = (f >> 3) & 63, t = (f >> 9) & 7, c = f >> 12;
    int k = c * 32 + (l >> 4) * 8 + j;
    int n = t * 16 + (l & 15);
    float v = trans ? w[n * HID + k] : w[k * HID + n];
    pk[f] = (__bf16)v;
}

__global__ __launch_bounds__(256) void cast_bf16_kernel(const float* __restrict__ x,
                                                        __bf16* __restrict__ o) {
    int i = blockIdx.x * 256 + threadIdx.x;   // NH/4 threads
    float4 v = ((const float4*)x)[i];
    bf16x4 b;
    b[0] = (__bf16)v.x; b[1] = (__bf16)v.y; b[2] = (__bf16)v.z; b[3] = (__bf16)v.w;
    ((bf16x4*)o)[i] = b;
}

// xproj GEMM (runs twice): xp_bf = A @ B (bf16 pre-tanh), st_bf = tanh(...).
__global__ __launch_bounds__(256) void mfma_gemm_kernel(const __bf16* A,
                                                        const __bf16* __restrict__ Bpk,
                                                        __bf16* __restrict__ xp_bf,
                                                        __bf16* st_bf) {
    __shared__ float tile[4][16][132];
    int tid = threadIdx.x;
    int wv = tid >> 6, lane = tid & 63;
    int q = lane >> 4, cl = lane & 15;

    int row_a = blockIdx.x * 64 + wv * 16 + cl;
    bf16x8 a[4];
#pragma unroll
    for (int c = 0; c < 4; ++c)
        a[c] = *(const bf16x8*)(A + (size_t)row_a * HID + c * 32 + q * 8);

#pragma unroll
    for (int t = 0; t < 8; ++t) {
        floatx4 acc_t = {0.f, 0.f, 0.f, 0.f};
#pragma unroll
        for (int c = 0; c < 4; ++c) {
            bf16x8 b = *(const bf16x8*)(Bpk + (((c * 8 + t) * 64 + lane) << 3));
            acc_t = __builtin_amdgcn_mfma_f32_16x16x32_bf16(a[c], b, acc_t, 0, 0, 0);
        }
#pragma unroll
        for (int r = 0; r < 4; ++r)
            tile[wv][q * 4 + r][t * 16 + cl] = acc_t[r];
    }
    int row = lane >> 2, seg = lane & 3;
    size_t goff = (size_t)(blockIdx.x * 64 + wv * 16 + row) * HID + seg * 32;
    float v[32];
#pragma unroll
    for (int j = 0; j < 8; ++j) {
        floatx4 t4 = *(floatx4*)&tile[wv][row][seg * 32 + j * 4];
        v[j * 4] = t4[0]; v[j * 4 + 1] = t4[1]; v[j * 4 + 2] = t4[2]; v[j * 4 + 3] = t4[3];
    }
#pragma unroll
    for (int j = 0; j < 4; ++j) {
        bf16x8 o;
#pragma unroll
        for (int k = 0; k < 8; ++k) o[k] = (__bf16)v[j * 8 + k];
        *(bf16x8*)(xp_bf + goff + j * 8) = o;   // pre-tanh, bf16
    }
#pragma unroll
    for (int i = 0; i < 32; ++i) v[i] = tanhf(v[i]);
#pragma unroll
    for (int j = 0; j < 4; ++j) {
        bf16x8 o;
#pragma unroll
        for (int k = 0; k < 8; ++k) o[k] = (__bf16)v[j * 8 + k];
        *(bf16x8*)(st_bf + goff + j * 8) = o;
    }
}

// Fused iteration: state_out = tanh(xproj + gather(state_in) @ W).
// PHASED gather: each node's ELL entries are pre-bucketed by source range
// (4 buckets x 10000 nodes = 2.56 MB of full 256B rows). All blocks walk the
// buckets in the same order inside ONE kernel (no extra launches/scratch), so
// at any instant the gather working set ~fits a 4 MiB per-XCD L2. Round-up pad
// slots hit the always-hot zero row at node N_NODES. f32 accumulation across
// all buckets -> numerics identical to the unbucketed kernel modulo sum order
// (which was already atomic-insertion-arbitrary).
__global__ __launch_bounds__(256, 8) void fused_iter_kernel(
    const __bf16* __restrict__ state_in,
    __bf16* __restrict__ state_out,
    const int* __restrict__ ell,
    const int* __restrict__ deg,
    const __bf16* __restrict__ Bpk,
    const __bf16* __restrict__ xproj,
    float* __restrict__ st_f32) {
    __shared__ __align__(16) char smem[10496];
    int(*ell_lds)[96] = (int(*)[96])smem;                    // [16][4 buckets x 24]: 6144 B
    __bf16(*aggr_lds)[136] = (__bf16(*)[136])(smem + 6144);  // [16][136]: 4352 B
    float(*tile)[132] = (float(*)[132])smem;                 // [16][132] f32 overlay: 8448 B

    int tid = threadIdx.x;
    int wv = tid >> 6, lane = tid & 63;
    int q = lane >> 4, f = lane & 15;
    int nb = blockIdx.x * NPB;

    int dpk = deg[nb + f];   // packed per-bucket counts (already clamped)
    // per-bucket block max via 16-lane butterfly
    int ns[BUCK];
#pragma unroll
    for (int p = 0; p < BUCK; ++p) {
        int b = (dpk >> (p * 8)) & 255;
#pragma unroll
        for (int m = 1; m <= 8; m <<= 1) {
            int o = __shfl_xor(b, m);
            b = o > b ? o : b;
        }
        ns[p] = (b + 3) & ~3;
    }

    // stage ELL: per bucket, 16 rows x 5 int4-groups, masked to block max
    {
        int n2 = tid & 15, g = tid >> 4;
        if (g < 5) {
#pragma unroll
            for (int p = 0; p < BUCK; ++p)
                if (g * 4 < ns[p])
                    *(int4*)&ell_lds[n2][p * LBS + g * 4] =
                        *(const int4*)&ell[(size_t)(nb + n2) * ELLW + p * BSLOT + g * 4];
        }
    }
    __syncthreads();

    // ---- phase 1: quarter q of wave wv gathers node n = wv*4+q, bucket-ordered ----
    int n = wv * 4 + q;
    int cpk = __shfl(dpk, n);          // lane n holds packed counts of node nb+n
    float acc[8];
#pragma unroll
    for (int j = 0; j < 8; ++j) acc[j] = 0.f;
#pragma unroll
    for (int p = 0; p < BUCK; ++p) {
        int cnt = (cpk >> (p * 8)) & 255;
        int steps = (cnt + 3) >> 2;    // 4-granular; pads read the zero row (L2-hot)
        const int* eb = &ell_lds[n][p * LBS];
        for (int s = 0; s < steps; ++s) {
            int b0 = s * 4;
            int idx[4];
#pragma unroll
            for (int u = 0; u < 4; ++u) idx[u] = eb[b0 + u];
            bf16x8 v[4];
#pragma unroll
            for (int u = 0; u < 4; ++u)
                v[u] = *(const bf16x8*)(state_in + (size_t)idx[u] * HID + f * 8);
#pragma unroll
            for (int j = 0; j < 8; ++j)
                acc[j] += ((float)v[0][j] + (float)v[1][j]) + ((float)v[2][j] + (float)v[3][j]);
        }
    }
    {
        bf16x8 o;
#pragma unroll
        for (int j = 0; j < 8; ++j) o[j] = (__bf16)acc[j];
        *(bf16x8*)&aggr_lds[n][f * 8] = o;
    }
    __syncthreads();

    // ---- phase 2: M=16 GEMM; wave wv owns output cols wv*32 .. +31 ----
    bf16x8 a[4];
#pragma unroll
    for (int c = 0; c < 4; ++c)
        a[c] = *(const bf16x8*)&aggr_lds[f][c * 32 + q * 8];
    __syncthreads();   // overlay safety: aggr/ell reads done before tile writes

#pragma unroll
    for (int tl = 0; tl < 2; ++tl) {
        int t = wv * 2 + tl;
        floatx4 acc_t = {0.f, 0.f, 0.f, 0.f};
#pragma unroll
        for (int c = 0; c < 4; ++c) {
            bf16x8 b = *(const bf16x8*)(Bpk + (((c * 8 + t) * 64 + lane) << 3));
            acc_t = __builtin_amdgcn_mfma_f32_16x16x32_bf16(a[c], b, acc_t, 0, 0, 0);
        }
#pragma unroll
        for (int r = 0; r < 4; ++r)
            tile[q * 4 + r][t * 16 + f] = acc_t[r];
    }

    // epilogue (wave-private cols): rows 0..15, cols wv*32 + (lane&3)*8 .. +7
    int row = lane >> 2, seg = lane & 3;
    size_t goff = (size_t)(nb + row) * HID + wv * 32 + seg * 8;
    int lcol = wv * 32 + seg * 8;
    float v[8];
    bf16x8 bx = *(const bf16x8*)(xproj + goff);
#pragma unroll
    for (int j = 0; j < 2; ++j) {
        floatx4 t4 = *(floatx4*)&tile[row][lcol + j * 4];
        v[j * 4] = t4[0]; v[j * 4 + 1] = t4[1]; v[j * 4 + 2] = t4[2]; v[j * 4 + 3] = t4[3];
    }
#pragma unroll
    for (int k = 0; k < 8; ++k) v[k] = tanhf(v[k] + (float)bx[k]);
    {
        bf16x8 o;
#pragma unroll
        for (int k = 0; k < 8; ++k) o[k] = (__bf16)v[k];
        *(bf16x8*)(state_out + goff) = o;
    }
    if (st_f32) {
#pragma unroll
        for (int j = 0; j < 2; ++j) {
            float4 o = {v[j * 4], v[j * 4 + 1], v[j * 4 + 2], v[j * 4 + 3]};
            *(float4*)(st_f32 + goff + j * 4) = o;
        }
    }
}

extern "C" void kernel_launch(void* const* d_in, const int* in_sizes, int n_in,
                              void* d_out, int out_size, void* d_ws, size_t ws_size,
                              hipStream_t stream) {
    const int* ei = (const int*)d_in[0];       // edge_index [2][E]
    const float* x = (const float*)d_in[1];    // [N][128] f32
    const float* w_in0 = (const float*)d_in[2];
    const float* w_rec0 = (const float*)d_in[3];
    const float* w_in1 = (const float*)d_in[4];
    const float* w_rec1 = (const float*)d_in[5];
    float* out = (float*)d_out;

    // workspace carve (~50 MB total)
    __bf16* xproj_bf = (__bf16*)d_ws;              // NH bf16 (10.24 MB)
    __bf16* stateA = xproj_bf + NH;                // NH + HID bf16 (pad row)
    __bf16* stateB = stateA + NH + HID;            // NH + HID bf16 (pad row); x_bf first
    __bf16* packs = stateB + NH + HID;             // 4 x 16384 bf16
    int* deg = (int*)(packs + 4 * 16384);          // N (packed bucket counts)
    int* degp = deg + N_NODES;                     // N*DSTRIDE (5.12 MB, padded counters)
    int* ell = degp + N_NODES * DSTRIDE;           // N*ELLW (12.8 MB, bucketed)
    __bf16* pk_in0 = packs;
    __bf16* pk_rec0 = packs + 16384;
    __bf16* pk_in1 = packs + 2 * 16384;
    __bf16* pk_rec1 = packs + 3 * 16384;

    init_kernel<<<N_NODES * ELLW / 4 / 256, 256, 0, stream>>>(ell, degp,
                                                              stateA + NH, stateB + NH);
    build_ell_kernel<<<N_EDGES / 256, 256, 0, stream>>>(ei, degp, ell);
    compact_deg_kernel<<<(N_NODES + 255) / 256, 256, 0, stream>>>(degp, deg);
    pack_w_kernel<<<64, 256, 0, stream>>>(w_in0, pk_in0, 1);   // B = w_in0^T
    pack_w_kernel<<<64, 256, 0, stream>>>(w_rec0, pk_rec0, 0); // B = w_rec0
    pack_w_kernel<<<64, 256, 0, stream>>>(w_in1, pk_in1, 1);
    pack_w_kernel<<<64, 256, 0, stream>>>(w_rec1, pk_rec1, 0);
    cast_bf16_kernel<<<NH / 4 / 256, 256, 0, stream>>>(x, stateB);  // x_bf in stateB

    for (int layer = 0; layer < 2; ++layer) {
        const __bf16* pk_in = layer ? pk_in1 : pk_in0;
        const __bf16* pk_rec = layer ? pk_rec1 : pk_rec0;
        // xproj = (layer ? h0 : x_bf) @ w_in^T ; stateA = tanh(xproj).
        // layer 1: A aliases st_bf (each wave reads its own rows first — safe).
        const __bf16* xin = layer ? stateA : stateB;
        mfma_gemm_kernel<<<625, 256, 0, stream>>>(xin, pk_in, xproj_bf, stateA);
        // 8 ping-pong iterations: A->B, B->A, ... ends in stateA.
        for (int it = 0; it < ITERS; ++it) {
            const __bf16* sin = (it & 1) ? stateB : stateA;
            __bf16* sout = (it & 1) ? stateA : stateB;
            float* f32out = (layer == 1 && it == ITERS - 1) ? out : nullptr;
            fused_iter_kernel<<<FBLK, 256, 0, stream>>>(sin, sout, ell, deg,
                                                        pk_rec, xproj_bf, f32out);
        }
    }
}

// Round 10
// 534.557 us; speedup vs baseline: 1.3004x; 1.1301x over previous
//
#include <hip/hip_runtime.h>
#include <math.h>

#define N_NODES 40000
#define N_EDGES 640000
#define HID 128
#define MAXW 64      // in-degree ~ Poisson(16); P(deg > 64) ~ 1e-19 -> never drops edges
#define ITERS 8      // full iterations after initial state = tanh(xproj)
#define NH (N_NODES * HID)
#define NPB 16                  // nodes per fused block
#define FBLK (N_NODES / NPB)    // 2500 fused blocks
#define DSTRIDE 32              // degree-counter pad: 1 counter per 128B line

typedef __bf16 bf16x8 __attribute__((ext_vector_type(8)));
typedef __bf16 bf16x4 __attribute__((ext_vector_type(4)));
typedef float floatx4 __attribute__((ext_vector_type(4)));

// Fill ELL with pad index N_NODES, zero padded deg counters, zero state pad rows.
__global__ __launch_bounds__(256) void init_kernel(int* __restrict__ ell,
                                                   int* __restrict__ degp,
                                                   __bf16* __restrict__ padA,
                                                   __bf16* __restrict__ padB) {
    int i = blockIdx.x * 256 + threadIdx.x;   // N_EDGES threads
    int4 pad = {N_NODES, N_NODES, N_NODES, N_NODES};
    ((int4*)ell)[i] = pad;                    // N*MAXW/4 = 640000 int4 exactly
    if (i < N_NODES * DSTRIDE / 4) {
        int4 z = {0, 0, 0, 0};
        ((int4*)degp)[i] = z;                 // 320000 int4
    }
    if (i < HID / 8) {
        bf16x8 z;
#pragma unroll
        for (int j = 0; j < 8; ++j) z[j] = (__bf16)0.f;
        ((bf16x8*)padA)[i] = z;
        ((bf16x8*)padB)[i] = z;
    }
}

// Degree counters padded to one per 128B L2 line: 16 counters/line serialized
// ~256 atomics/line -> 52us (rounds 6/7 lesson); padded -> ~15us.
__global__ __launch_bounds__(256) void build_ell_kernel(const int* __restrict__ ei,
                                                        int* __restrict__ degp,
                                                        int* __restrict__ ell) {
    int e = blockIdx.x * 256 + threadIdx.x;
    if (e >= N_EDGES) return;
    int s = ei[e];            // src
    int d = ei[N_EDGES + e];  // dst
    int c = atomicAdd(&degp[d * DSTRIDE], 1);
    if (c < MAXW) ell[d * MAXW + c] = s;
}

__global__ __launch_bounds__(256) void compact_deg_kernel(const int* __restrict__ degp,
                                                          int* __restrict__ deg) {
    int i = blockIdx.x * 256 + threadIdx.x;
    if (i >= N_NODES) return;
    int d = degp[i * DSTRIDE];
    deg[i] = d > MAXW ? MAXW : d;
}

// Pack all 4 weights (W or W^T) into B-fragment order for mfma_f32_16x16x32_bf16
// in ONE launch: pk[((c*8+t)*64 + lane)*8 + j] = B[k][n],
// k = c*32 + (lane>>4)*8 + j, n = t*16 + (lane&15). sel 0..3 = in0,rec0,in1,rec1;
// trans (B = W^T) for the in-weights.
__global__ __launch_bounds__(256) void pack_all_kernel(const float* __restrict__ w_in0,
                                                       const float* __restrict__ w_rec0,
                                                       const float* __restrict__ w_in1,
                                                       const float* __restrict__ w_rec1,
                                                       __bf16* __restrict__ pk) {
    int f = blockIdx.x * 256 + threadIdx.x;  // 4 x 16384 total
    int sel = f >> 14;
    int g = f & 16383;
    int j = g & 7, l = (g >> 3) & 63, t = (g >> 9) & 7, c = g >> 12;
    int k = c * 32 + (l >> 4) * 8 + j;
    int n = t * 16 + (l & 15);
    const float* w = sel == 0 ? w_in0 : sel == 1 ? w_rec0 : sel == 2 ? w_in1 : w_rec1;
    int trans = (sel & 1) ^ 1;               // in-weights transposed
    float v = trans ? w[n * HID + k] : w[k * HID + n];
    pk[f] = (__bf16)v;
}

__global__ __launch_bounds__(256) void cast_bf16_kernel(const float* __restrict__ x,
                                                        __bf16* __restrict__ o) {
    int i = blockIdx.x * 256 + threadIdx.x;   // NH/4 threads
    float4 v = ((const float4*)x)[i];
    bf16x4 b;
    b[0] = (__bf16)v.x; b[1] = (__bf16)v.y; b[2] = (__bf16)v.z; b[3] = (__bf16)v.w;
    ((bf16x4*)o)[i] = b;
}

// xproj GEMM (runs twice): xp_bf = A @ B (bf16 pre-tanh), st_bf = tanh(...).
__global__ __launch_bounds__(256) void mfma_gemm_kernel(const __bf16* A,
                                                        const __bf16* __restrict__ Bpk,
                                                        __bf16* __restrict__ xp_bf,
                                                        __bf16* st_bf) {
    __shared__ float tile[4][16][132];
    int tid = threadIdx.x;
    int wv = tid >> 6, lane = tid & 63;
    int q = lane >> 4, cl = lane & 15;

    int row_a = blockIdx.x * 64 + wv * 16 + cl;
    bf16x8 a[4];
#pragma unroll
    for (int c = 0; c < 4; ++c)
        a[c] = *(const bf16x8*)(A + (size_t)row_a * HID + c * 32 + q * 8);

#pragma unroll
    for (int t = 0; t < 8; ++t) {
        floatx4 acc_t = {0.f, 0.f, 0.f, 0.f};
#pragma unroll
        for (int c = 0; c < 4; ++c) {
            bf16x8 b = *(const bf16x8*)(Bpk + (((c * 8 + t) * 64 + lane) << 3));
            acc_t = __builtin_amdgcn_mfma_f32_16x16x32_bf16(a[c], b, acc_t, 0, 0, 0);
        }
#pragma unroll
        for (int r = 0; r < 4; ++r)
            tile[wv][q * 4 + r][t * 16 + cl] = acc_t[r];
    }
    int row = lane >> 2, seg = lane & 3;
    size_t goff = (size_t)(blockIdx.x * 64 + wv * 16 + row) * HID + seg * 32;
    float v[32];
#pragma unroll
    for (int j = 0; j < 8; ++j) {
        floatx4 t4 = *(floatx4*)&tile[wv][row][seg * 32 + j * 4];
        v[j * 4] = t4[0]; v[j * 4 + 1] = t4[1]; v[j * 4 + 2] = t4[2]; v[j * 4 + 3] = t4[3];
    }
#pragma unroll
    for (int j = 0; j < 4; ++j) {
        bf16x8 o;
#pragma unroll
        for (int k = 0; k < 8; ++k) o[k] = (__bf16)v[j * 8 + k];
        *(bf16x8*)(xp_bf + goff + j * 8) = o;   // pre-tanh, bf16
    }
#pragma unroll
    for (int i = 0; i < 32; ++i) v[i] = tanhf(v[i]);
#pragma unroll
    for (int j = 0; j < 4; ++j) {
        bf16x8 o;
#pragma unroll
        for (int k = 0; k < 8; ++k) o[k] = (__bf16)v[j * 8 + k];
        *(bf16x8*)(st_bf + goff + j * 8) = o;
    }
}

// Fused iteration: state_out = tanh(xproj + gather(state_in) @ W).
// 16 nodes/block, 2500 blocks, 8.7 KB LDS, <=64 VGPR -> 32 waves/CU.
// Gather: one node per 16-lane quarter, exact 4-granular trip counts;
// ELL staged to block-max degree (in-wave butterfly, no atomics).
// Pad slots hit the zero row at state_in + N_NODES*HID.
// At ~28.5us/iter this moves ~187MB logical at ~6.5 TB/s effective — the
// measured service-rate ceiling for a 10.24MB randomly-gathered state
// (invariant across feature-slice/two-pass/bucketed restructures, r2/r8/r9).
__global__ __launch_bounds__(256, 8) void fused_iter_kernel(
    const __bf16* __restrict__ state_in,
    __bf16* __restrict__ state_out,
    const int* __restrict__ ell,
    const int* __restrict__ deg,
    const __bf16* __restrict__ Bpk,
    const __bf16* __restrict__ xproj,
    float* __restrict__ st_f32) {
    __shared__ __align__(16) char smem[8704];
    int(*ell_lds)[68] = (int(*)[68])smem;                    // [16][68] int: 4352 B
    __bf16(*aggr_lds)[136] = (__bf16(*)[136])(smem + 4352);  // [16][136]: 4352 B
    float(*tile)[132] = (float(*)[132])smem;                 // [16][132] f32: 8448 B

    int tid = threadIdx.x;
    int wv = tid >> 6, lane = tid & 63;
    int q = lane >> 4, f = lane & 15;
    int nb = blockIdx.x * NPB;

    int degv = deg[nb + f];   // already clamped to MAXW
    // block max degree via 16-lane butterfly (no atomics)
    int bmx = degv;
#pragma unroll
    for (int m = 1; m <= 8; m <<= 1) {
        int o = __shfl_xor(bmx, m);
        bmx = o > bmx ? o : bmx;
    }
    int nslots = (bmx + 3) & ~3;

    // stage ELL: 256 threads = 16 rows x 16 int4-groups, one shot, masked
    {
        int n = tid & 15, g = tid >> 4;
        if (g * 4 < nslots)
            *(int4*)&ell_lds[n][g * 4] = *(const int4*)&ell[(size_t)(nb + n) * MAXW + g * 4];
    }
    __syncthreads();

    // ---- phase 1: quarter q of wave wv gathers node n = wv*4+q ----
    int n = wv * 4 + q;
    int cn = __shfl(degv, n);          // lane n holds deg[nb+n]
    int steps = (cn + 3) >> 2;         // exact 4-granular trip count
    float acc[8];
#pragma unroll
    for (int j = 0; j < 8; ++j) acc[j] = 0.f;
    for (int s = 0; s < steps; ++s) {
        int b0 = s * 4;
        int idx[4];
#pragma unroll
        for (int u = 0; u < 4; ++u) idx[u] = ell_lds[n][b0 + u];
        bf16x8 v[4];
#pragma unroll
        for (int u = 0; u < 4; ++u)
            v[u] = *(const bf16x8*)(state_in + (size_t)idx[u] * HID + f * 8);
#pragma unroll
        for (int j = 0; j < 8; ++j)
            acc[j] += ((float)v[0][j] + (float)v[1][j]) + ((float)v[2][j] + (float)v[3][j]);
    }
    {
        bf16x8 o;
#pragma unroll
        for (int j = 0; j < 8; ++j) o[j] = (__bf16)acc[j];
        *(bf16x8*)&aggr_lds[n][f * 8] = o;
    }
    __syncthreads();

    // ---- phase 2: M=16 GEMM; wave wv owns output cols wv*32 .. +31 ----
    bf16x8 a[4];
#pragma unroll
    for (int c = 0; c < 4; ++c)
        a[c] = *(const bf16x8*)&aggr_lds[f][c * 32 + q * 8];
    __syncthreads();   // overlay safety: aggr/ell reads done before tile writes

#pragma unroll
    for (int tl = 0; tl < 2; ++tl) {
        int t = wv * 2 + tl;
        floatx4 acc_t = {0.f, 0.f, 0.f, 0.f};
#pragma unroll
        for (int c = 0; c < 4; ++c) {
            bf16x8 b = *(const bf16x8*)(Bpk + (((c * 8 + t) * 64 + lane) << 3));
            acc_t = __builtin_amdgcn_mfma_f32_16x16x32_bf16(a[c], b, acc_t, 0, 0, 0);
        }
#pragma unroll
        for (int r = 0; r < 4; ++r)
            tile[q * 4 + r][t * 16 + f] = acc_t[r];
    }

    // epilogue (wave-private cols): rows 0..15, cols wv*32 + (lane&3)*8 .. +7
    int row = lane >> 2, seg = lane & 3;
    size_t goff = (size_t)(nb + row) * HID + wv * 32 + seg * 8;
    int lcol = wv * 32 + seg * 8;
    float v[8];
    bf16x8 bx = *(const bf16x8*)(xproj + goff);
#pragma unroll
    for (int j = 0; j < 2; ++j) {
        floatx4 t4 = *(floatx4*)&tile[row][lcol + j * 4];
        v[j * 4] = t4[0]; v[j * 4 + 1] = t4[1]; v[j * 4 + 2] = t4[2]; v[j * 4 + 3] = t4[3];
    }
#pragma unroll
    for (int k = 0; k < 8; ++k) v[k] = tanhf(v[k] + (float)bx[k]);
    {
        bf16x8 o;
#pragma unroll
        for (int k = 0; k < 8; ++k) o[k] = (__bf16)v[k];
        *(bf16x8*)(state_out + goff) = o;
    }
    if (st_f32) {
#pragma unroll
        for (int j = 0; j < 2; ++j) {
            float4 o = {v[j * 4], v[j * 4 + 1], v[j * 4 + 2], v[j * 4 + 3]};
            *(float4*)(st_f32 + goff + j * 4) = o;
        }
    }
}

extern "C" void kernel_launch(void* const* d_in, const int* in_sizes, int n_in,
                              void* d_out, int out_size, void* d_ws, size_t ws_size,
                              hipStream_t stream) {
    const int* ei = (const int*)d_in[0];       // edge_index [2][E]
    const float* x = (const float*)d_in[1];    // [N][128] f32
    const float* w_in0 = (const float*)d_in[2];
    const float* w_rec0 = (const float*)d_in[3];
    const float* w_in1 = (const float*)d_in[4];
    const float* w_rec1 = (const float*)d_in[5];
    float* out = (float*)d_out;

    // workspace carve (~47 MB total)
    __bf16* xproj_bf = (__bf16*)d_ws;              // NH bf16 (10.24 MB)
    __bf16* stateA = xproj_bf + NH;                // NH + HID bf16 (pad row)
    __bf16* stateB = stateA + NH + HID;            // NH + HID bf16 (pad row); x_bf first
    __bf16* packs = stateB + NH + HID;             // 4 x 16384 bf16
    int* deg = (int*)(packs + 4 * 16384);          // N (compact)
    int* degp = deg + N_NODES;                     // N*DSTRIDE (5.12 MB, padded counters)
    int* ell = degp + N_NODES * DSTRIDE;           // N*MAXW (10.24 MB)
    __bf16* pk_in0 = packs;
    __bf16* pk_rec0 = packs + 16384;
    __bf16* pk_in1 = packs + 2 * 16384;
    __bf16* pk_rec1 = packs + 3 * 16384;

    init_kernel<<<N_EDGES / 256, 256, 0, stream>>>(ell, degp, stateA + NH, stateB + NH);
    build_ell_kernel<<<N_EDGES / 256, 256, 0, stream>>>(ei, degp, ell);
    compact_deg_kernel<<<(N_NODES + 255) / 256, 256, 0, stream>>>(degp, deg);
    pack_all_kernel<<<256, 256, 0, stream>>>(w_in0, w_rec0, w_in1, w_rec1, packs);
    cast_bf16_kernel<<<NH / 4 / 256, 256, 0, stream>>>(x, stateB);  // x_bf in stateB

    for (int layer = 0; layer < 2; ++layer) {
        const __bf16* pk_in = layer ? pk_in1 : pk_in0;
        const __bf16* pk_rec = layer ? pk_rec1 : pk_rec0;
        // xproj = (layer ? h0 : x_bf) @ w_in^T ; stateA = tanh(xproj).
        // layer 1: A aliases st_bf (each wave reads its own rows first — safe).
        const __bf16* xin = layer ? stateA : stateB;
        mfma_gemm_kernel<<<625, 256, 0, stream>>>(xin, pk_in, xproj_bf, stateA);
        // 8 ping-pong iterations: A->B, B->A, ... ends in stateA.
        for (int it = 0; it < ITERS; ++it) {
            const __bf16* sin = (it & 1) ? stateB : stateA;
            __bf16* sout = (it & 1) ? stateA : stateB;
            float* f32out = (layer == 1 && it == ITERS - 1) ? out : nullptr;
            fused_iter_kernel<<<FBLK, 256, 0, stream>>>(sin, sout, ell, deg,
                                                        pk_rec, xproj_bf, f32out);
        }
    }
}